// Round 1
// 3021.753 us; speedup vs baseline: 3.9389x; 3.9389x over previous
//
#include <hip/hip_runtime.h>
#include <math.h>

#define EPT 4  // edges processed concurrently per wave

__device__ __forceinline__ float silu_f(float v) { return v / (1.0f + __expf(-v)); }
// broadcast lane l's value to all lanes (l must be wave-uniform) — v_readlane, no LDS pipe
__device__ __forceinline__ float bcastf(float v, int l) {
    return __int_as_float(__builtin_amdgcn_readlane(__float_as_int(v), l));
}

// lane j owns output feature j; EPT edges share each LDS weight read.
// 16 waves/block share one 64KB LDS weight copy -> 16 waves/CU (4/SIMD) at VGPR<=128.
// One-group-deep software pipeline: idx loads at loop top, hh/x gathers after layer 1.
__global__ __launch_bounds__(1024, 4) void egnn_edge_kernel(
    const float* __restrict__ x,
    const float* __restrict__ hh,
    const int* __restrict__ src_idx,
    const int* __restrict__ dst_idx,
    const float* __restrict__ W1, const float* __restrict__ b1,
    const float* __restrict__ W2, const float* __restrict__ b2,
    const float* __restrict__ W3, const float* __restrict__ b3,
    const float* __restrict__ W4,
    float* __restrict__ out_radial,   // [E]
    float* __restrict__ out_trans,    // [E,3]
    float* __restrict__ out_ef,       // [E,64]
    int n_edges)
{
    __shared__ float sW1[127 * 64];   // W1 rows 1..127 (rows 0 & 128 live in regs)
    __shared__ float sW2[64 * 64];
    __shared__ float sW3[64 * 64];    // total 65280 B < 65536 B static cap

    const int tid = threadIdx.x;
    for (int i = tid; i < 127 * 64; i += 1024) sW1[i] = W1[64 + i];
    for (int i = tid; i < 64 * 64; i += 1024) { sW2[i] = W2[i]; sW3[i] = W3[i]; }
    __syncthreads();

    const int lane = tid & 63;
    const float w1r    = W1[lane];             // W1 row 0   (radial)
    const float w1last = W1[128 * 64 + lane];  // W1 row 128 (hd[63])
    const float b1l = b1[lane], b2l = b2[lane], b3l = b3[lane];
    const float w4l = W4[lane];

    const int  wave = tid >> 6;
    const long wid  = (long)blockIdx.x * 16 + wave;
    const long wtot = (long)gridDim.x * 16;
    const long ngrp = ((long)n_edges + EPT - 1) / EPT;
    if (wid >= ngrp) return;  // no barriers after this point

    // ---------- prologue: unpipelined load of first group ----------
    float hs[EPT], hd[EPT], dx0[EPT], dx1[EPT], dx2[EPT], rad[EPT];
    {
        int sc[EPT], dc[EPT];
        #pragma unroll
        for (int i = 0; i < EPT; ++i) {
            long e = wid * EPT + i; if (e >= n_edges) e = n_edges - 1;
            sc[i] = src_idx[e]; dc[i] = dst_idx[e];
        }
        #pragma unroll
        for (int i = 0; i < EPT; ++i) {
            hs[i] = hh[(long)sc[i] * 64 + lane];
            hd[i] = hh[(long)dc[i] * 64 + lane];
        }
        #pragma unroll
        for (int i = 0; i < EPT; ++i) {
            const float xs0 = x[sc[i]*3+0], xs1 = x[sc[i]*3+1], xs2 = x[sc[i]*3+2];
            const float xd0 = x[dc[i]*3+0], xd1 = x[dc[i]*3+1], xd2 = x[dc[i]*3+2];
            dx0[i] = xs0-xd0; dx1[i] = xs1-xd1; dx2[i] = xs2-xd2;
            rad[i] = dx0[i]*dx0[i] + dx1[i]*dx1[i] + dx2[i]*dx2[i];
        }
    }

    for (long g = wid; g < ngrp; g += wtot) {
        // ---- issue next-group INDEX loads (consumed ~2.5K cycles later) ----
        long gn = g + wtot; if (gn >= ngrp) gn = ngrp - 1;  // clamp: loads stay valid
        int sn[EPT], dn[EPT];
        #pragma unroll
        for (int i = 0; i < EPT; ++i) {
            long e = gn * EPT + i; if (e >= n_edges) e = n_edges - 1;
            sn[i] = src_idx[e]; dn[i] = dst_idx[e];
        }

        // ---- layer 1: h1 = silu([radial, hs, hd] @ W1 + b1) ----
        // radial term folded in AFTER the k-loops so x latency never stalls startup
        float acc[EPT];
        #pragma unroll
        for (int i = 0; i < EPT; ++i) acc[i] = b1l;
        #pragma unroll 8
        for (int k = 0; k < 64; ++k) {
            const float w = sW1[k * 64 + lane];            // W1 row 1+k
            #pragma unroll
            for (int i = 0; i < EPT; ++i) acc[i] = fmaf(bcastf(hs[i], k), w, acc[i]);
        }
        #pragma unroll 8
        for (int k = 0; k < 63; ++k) {
            const float w = sW1[(64 + k) * 64 + lane];     // W1 row 65+k
            #pragma unroll
            for (int i = 0; i < EPT; ++i) acc[i] = fmaf(bcastf(hd[i], k), w, acc[i]);
        }

        // ---- issue next-group GATHERS; latency hides under layers 2-4 ----
        float hsn[EPT], hdn[EPT];
        float xs0n[EPT], xs1n[EPT], xs2n[EPT], xd0n[EPT], xd1n[EPT], xd2n[EPT];
        #pragma unroll
        for (int i = 0; i < EPT; ++i) {
            hsn[i] = hh[(long)sn[i] * 64 + lane];
            hdn[i] = hh[(long)dn[i] * 64 + lane];
        }
        #pragma unroll
        for (int i = 0; i < EPT; ++i) {
            xs0n[i] = x[sn[i]*3+0]; xs1n[i] = x[sn[i]*3+1]; xs2n[i] = x[sn[i]*3+2];
            xd0n[i] = x[dn[i]*3+0]; xd1n[i] = x[dn[i]*3+1]; xd2n[i] = x[dn[i]*3+2];
        }

        float h1[EPT];
        #pragma unroll
        for (int i = 0; i < EPT; ++i) {
            acc[i] = fmaf(rad[i], w1r, acc[i]);
            acc[i] = fmaf(bcastf(hd[i], 63), w1last, acc[i]);
            h1[i] = silu_f(acc[i]);
        }

        // ---- layer 2: ef = silu(h1 @ W2 + b2) ----
        float ef[EPT];
        #pragma unroll
        for (int i = 0; i < EPT; ++i) acc[i] = b2l;
        #pragma unroll 8
        for (int k = 0; k < 64; ++k) {
            const float w = sW2[k * 64 + lane];
            #pragma unroll
            for (int i = 0; i < EPT; ++i) acc[i] = fmaf(bcastf(h1[i], k), w, acc[i]);
        }
        #pragma unroll
        for (int i = 0; i < EPT; ++i) ef[i] = silu_f(acc[i]);

        // ---- layer 3: h3 = silu(ef @ W3 + b3) ----
        float h3[EPT];
        #pragma unroll
        for (int i = 0; i < EPT; ++i) acc[i] = b3l;
        #pragma unroll 8
        for (int k = 0; k < 64; ++k) {
            const float w = sW3[k * 64 + lane];
            #pragma unroll
            for (int i = 0; i < EPT; ++i) acc[i] = fmaf(bcastf(ef[i], k), w, acc[i]);
        }
        #pragma unroll
        for (int i = 0; i < EPT; ++i) h3[i] = silu_f(acc[i]);

        // ---- layer 4: scale = tanh(h3 @ W4) ----
        float scale[EPT];
        #pragma unroll
        for (int i = 0; i < EPT; ++i) {
            float p = h3[i] * w4l;
            #pragma unroll
            for (int off = 32; off > 0; off >>= 1) p += __shfl_xor(p, off);
            scale[i] = tanhf(p);
        }

        // ---- stores ----
        #pragma unroll
        for (int i = 0; i < EPT; ++i) {
            const long e = g * EPT + i;
            if (e < n_edges) {
                out_ef[e * 64 + lane] = ef[i];
                if (lane == 0) out_radial[e] = rad[i];
                if (lane < 3) {
                    const float inv = 1.0f / (sqrtf(rad[i]) + 1e-8f);
                    const float dd = (lane == 0) ? dx0[i] : ((lane == 1) ? dx1[i] : dx2[i]);
                    out_trans[e * 3 + lane] = dd * inv * scale[i];
                }
            }
        }

        // ---- fold next-group x and rotate pipeline registers ----
        #pragma unroll
        for (int i = 0; i < EPT; ++i) {
            dx0[i] = xs0n[i]-xd0n[i]; dx1[i] = xs1n[i]-xd1n[i]; dx2[i] = xs2n[i]-xd2n[i];
            rad[i] = dx0[i]*dx0[i] + dx1[i]*dx1[i] + dx2[i]*dx2[i];
            hs[i] = hsn[i]; hd[i] = hdn[i];
        }
    }
}

extern "C" void kernel_launch(void* const* d_in, const int* in_sizes, int n_in,
                              void* d_out, int out_size, void* d_ws, size_t ws_size,
                              hipStream_t stream) {
    const float* x   = (const float*)d_in[0];
    const float* hh  = (const float*)d_in[1];
    const int* src_idx = (const int*)d_in[2];
    const int* dst_idx = (const int*)d_in[3];
    const float* W1  = (const float*)d_in[4];
    const float* b1  = (const float*)d_in[5];
    const float* W2  = (const float*)d_in[6];
    const float* b2  = (const float*)d_in[7];
    const float* W3  = (const float*)d_in[8];
    const float* b3  = (const float*)d_in[9];
    const float* W4  = (const float*)d_in[10];

    const int E = in_sizes[2];

    float* out_radial = (float*)d_out;            // [E]
    float* out_trans  = out_radial + (long)E;     // [E,3]
    float* out_ef     = out_radial + (long)E * 4; // [E,64]

    // 1024-thread blocks: 16 waves share one LDS weight copy; 1 block/CU resident
    // (VGPR<=128 forced by __launch_bounds__), grid-stride over edge groups.
    dim3 grid(1024), block(1024);
    egnn_edge_kernel<<<grid, block, 0, stream>>>(
        x, hh, src_idx, dst_idx, W1, b1, W2, b2, W3, b3, W4,
        out_radial, out_trans, out_ef, E);
}

// Round 3
// 662.005 us; speedup vs baseline: 17.9793x; 4.5645x over previous
//
#include <hip/hip_runtime.h>
#include <math.h>

typedef _Float16 f16x8 __attribute__((ext_vector_type(8)));
typedef __fp16   pk16x2 __attribute__((ext_vector_type(2)));   // cvt_pkrtz return type
typedef float    f32x16 __attribute__((ext_vector_type(16)));
typedef unsigned int u32x4 __attribute__((ext_vector_type(4)));

__device__ __forceinline__ float silu_f(float v) { return v / (1.0f + __expf(-v)); }

__device__ __forceinline__ unsigned pkrtz(float a, float b) {
  pk16x2 h = __builtin_amdgcn_cvt_pkrtz(a, b);
  return __builtin_bit_cast(unsigned, h);
}
// gfx950: vdst.hi <-> vsrc.lo.  After: a = {a.lo, b.lo}, b = {a.hi, b.hi}.
__device__ __forceinline__ void plswap(unsigned &a, unsigned &b) {
  asm volatile("v_permlane32_swap_b32 %0, %1" : "+v"(a), "+v"(b));
}
__device__ __forceinline__ f16x8 frag4(unsigned r0, unsigned r1, unsigned r2, unsigned r3) {
  u32x4 u = {r0, r1, r2, r3};
  return __builtin_bit_cast(f16x8, u);
}
__device__ __forceinline__ f32x16 zero16() {
  f32x16 z;
  #pragma unroll
  for (int i = 0; i < 16; ++i) z[i] = 0.0f;
  return z;
}

// MFMA 32x32x16 f16 layouts (CDNA4):
//   A[32xK16]: row = lane&31, k = (lane>>5)*8 + j   (8 contiguous k per lane)
//   B[K16x32]: col = lane&31, k = (lane>>5)*8 + j
//   C[32x32] : col = lane&31, row = (r&3) + 8*(r>>2) + 4*(lane>>5), r=0..15
// We compute H^T = W^T @ X^T, so C cols = edges and C feeds next layer's B.
//
// K layout layer 1 (K=144, 9 ktiles): feats 0-63 = hh[src], 64-127 = hh[dst],
//   128 = radial (W1 row 0), 136 = 1.0 (bias row b1), rest zero-padded.
// K layout layers 2/3 (K=80, 5 ktiles): feats 0-63 = h, 64 = 1.0 (bias row).
#define NFRAG 38  // A1: 2m x 9t = 18 | A2: 2m x 5t = 10 | A3: 10

__global__ __launch_bounds__(256, 4) void egnn_edge_kernel(
    const float* __restrict__ x,
    const float* __restrict__ hh,
    const int* __restrict__ src_idx,
    const int* __restrict__ dst_idx,
    const float* __restrict__ W1, const float* __restrict__ b1,
    const float* __restrict__ W2, const float* __restrict__ b2,
    const float* __restrict__ W3, const float* __restrict__ b3,
    const float* __restrict__ W4,
    float* __restrict__ out_radial,   // [E]
    float* __restrict__ out_trans,    // [E,3]
    float* __restrict__ out_ef,       // [E,64]
    int n_edges)
{
    __shared__ __align__(16) unsigned short sA[NFRAG * 512];  // 38 KiB f16 frags
    __shared__ float sW4f[64];                                // W4 in C-layout order

    const int tid = threadIdx.x;

    // ---- pack W^T fragments into LDS (once per block) ----
    for (int idx = tid; idx < NFRAG * 64; idx += 256) {
        const int f = idx >> 6, l = idx & 63;
        const int fhi = l >> 5, row = l & 31;
        int layer, m, t;
        if (f < 18)      { layer = 1; m = f / 9;        t = f % 9; }
        else if (f < 28) { layer = 2; m = (f - 18) / 5; t = (f - 18) % 5; }
        else             { layer = 3; m = (f - 28) / 5; t = (f - 28) % 5; }
        const int row_out = m * 32 + row;
        #pragma unroll
        for (int j = 0; j < 8; ++j) {
            const int kf = t * 16 + fhi * 8 + j;
            float v = 0.0f;
            if (layer == 1) {
                if (kf < 128)       v = W1[(1 + kf) * 64 + row_out];  // hs/hd rows
                else if (kf == 128) v = W1[row_out];                  // radial row
                else if (kf == 136) v = b1[row_out];                  // bias row
            } else {
                const float* W = (layer == 2) ? W2 : W3;
                const float* b = (layer == 2) ? b2 : b3;
                if (kf < 64)       v = W[kf * 64 + row_out];
                else if (kf == 64) v = b[row_out];
            }
            sA[f * 512 + l * 8 + j] = __builtin_bit_cast(unsigned short, (_Float16)v);
        }
    }
    for (int i = tid; i < 64; i += 256) {
        const int fhi = i >> 5, k = i & 31;
        const int m = k >> 4, r = k & 15;
        sW4f[i] = W4[m * 32 + (r & 3) + 8 * (r >> 2) + 4 * fhi];
    }
    __syncthreads();

    const int lane = tid & 63;
    const int c  = lane & 31;   // edge slot within group (MFMA col)
    const int hi = lane >> 5;   // k-half
    const int wave = tid >> 6;
    const unsigned short* myA = sA + lane * 8;  // per-lane frag base (+f*512 elems)

    const long ngrp = ((long)n_edges + 31) >> 5;
    const long wid  = (long)blockIdx.x * 4 + wave;
    const long wtot = (long)gridDim.x * 4;

    for (long g = wid; g < ngrp; g += wtot) {
        const long eidx = g * 32 + c;
        const long e = (eidx < n_edges) ? eidx : (long)n_edges - 1;
        const bool valid = (eidx < n_edges);
        const int s = src_idx[e];
        const int d = dst_idx[e];

        const float dx0 = x[3*s+0] - x[3*d+0];
        const float dx1 = x[3*s+1] - x[3*d+1];
        const float dx2 = x[3*s+2] - x[3*d+2];
        const float radial = dx0*dx0 + dx1*dx1 + dx2*dx2;

        // ---- B1 fragments: lane holds 8 contiguous feats (k half = hi) ----
        const float4* hsp = reinterpret_cast<const float4*>(hh + (long)s * 64 + hi * 8);
        const float4* hdp = reinterpret_cast<const float4*>(hh + (long)d * 64 + hi * 8);
        unsigned B1[9][4];
        #pragma unroll
        for (int t = 0; t < 4; ++t) {
            float4 a = hsp[4*t], b = hsp[4*t + 1];
            B1[t][0] = pkrtz(a.x, a.y); B1[t][1] = pkrtz(a.z, a.w);
            B1[t][2] = pkrtz(b.x, b.y); B1[t][3] = pkrtz(b.z, b.w);
            float4 p = hdp[4*t], q = hdp[4*t + 1];
            B1[4+t][0] = pkrtz(p.x, p.y); B1[4+t][1] = pkrtz(p.z, p.w);
            B1[4+t][2] = pkrtz(q.x, q.y); B1[4+t][3] = pkrtz(q.z, q.w);
        }
        B1[8][0] = hi ? 0x00003C00u : pkrtz(radial, 0.0f);  // radial @k128, 1.0 @k136
        B1[8][1] = 0u; B1[8][2] = 0u; B1[8][3] = 0u;

        // ---- layer 1: C = W1^T @ X1^T  (bias via k=136) ----
        f32x16 acc0 = zero16(), acc1 = zero16();
        #pragma unroll
        for (int t = 0; t < 9; ++t) {
            f16x8 bt = frag4(B1[t][0], B1[t][1], B1[t][2], B1[t][3]);
            acc0 = __builtin_amdgcn_mfma_f32_32x32x16_f16(
                *(const f16x8*)(myA + (t)     * 512), bt, acc0, 0, 0, 0);
            acc1 = __builtin_amdgcn_mfma_f32_32x32x16_f16(
                *(const f16x8*)(myA + (9 + t) * 512), bt, acc1, 0, 0, 0);
        }
        f32x16 s0, s1;
        #pragma unroll
        for (int r = 0; r < 16; ++r) { s0[r] = silu_f(acc0[r]); s1[r] = silu_f(acc1[r]); }

        // ---- C-layout -> B-frag re-layout: cvt_pkrtz + permlane32_swap ----
        unsigned B2[4][4];
        #pragma unroll
        for (int tt = 0; tt < 2; ++tt) {
            unsigned L0 = pkrtz(s0[8*tt+0], s0[8*tt+1]), L1 = pkrtz(s0[8*tt+2], s0[8*tt+3]);
            unsigned H0 = pkrtz(s0[8*tt+4], s0[8*tt+5]), H1 = pkrtz(s0[8*tt+6], s0[8*tt+7]);
            plswap(L0, H0); plswap(L1, H1);
            B2[tt][0] = L0; B2[tt][1] = L1; B2[tt][2] = H0; B2[tt][3] = H1;
            unsigned M0 = pkrtz(s1[8*tt+0], s1[8*tt+1]), M1 = pkrtz(s1[8*tt+2], s1[8*tt+3]);
            unsigned N0 = pkrtz(s1[8*tt+4], s1[8*tt+5]), N1 = pkrtz(s1[8*tt+6], s1[8*tt+7]);
            plswap(M0, N0); plswap(M1, N1);
            B2[2+tt][0] = M0; B2[2+tt][1] = M1; B2[2+tt][2] = N0; B2[2+tt][3] = N1;
        }

        // ---- layer 2 (A frags 18..27; ktile4 = bias row x B=1) ----
        const unsigned bias_b0 = hi ? 0u : 0x00003C00u;  // 1.0 at k=64 (hi=0,j=0)
        f32x16 a20 = zero16(), a21 = zero16();
        #pragma unroll
        for (int t = 0; t < 4; ++t) {
            f16x8 bt = frag4(B2[t][0], B2[t][1], B2[t][2], B2[t][3]);
            a20 = __builtin_amdgcn_mfma_f32_32x32x16_f16(
                *(const f16x8*)(myA + (18 + t) * 512), bt, a20, 0, 0, 0);
            a21 = __builtin_amdgcn_mfma_f32_32x32x16_f16(
                *(const f16x8*)(myA + (23 + t) * 512), bt, a21, 0, 0, 0);
        }
        {
            f16x8 bb = frag4(bias_b0, 0u, 0u, 0u);
            a20 = __builtin_amdgcn_mfma_f32_32x32x16_f16(
                *(const f16x8*)(myA + 22 * 512), bb, a20, 0, 0, 0);
            a21 = __builtin_amdgcn_mfma_f32_32x32x16_f16(
                *(const f16x8*)(myA + 27 * 512), bb, a21, 0, 0, 0);
        }
        f32x16 e0s, e1s;
        #pragma unroll
        for (int r = 0; r < 16; ++r) { e0s[r] = silu_f(a20[r]); e1s[r] = silu_f(a21[r]); }

        // ---- store out_ef (f32), 16B chunks: feat = 8q + 4hi + i (+32 for e1s) ----
        if (valid) {
            float* efp = out_ef + e * 64 + hi * 4;
            #pragma unroll
            for (int q = 0; q < 4; ++q) {
                *reinterpret_cast<float4*>(efp + 8*q) =
                    make_float4(e0s[4*q+0], e0s[4*q+1], e0s[4*q+2], e0s[4*q+3]);
                *reinterpret_cast<float4*>(efp + 32 + 8*q) =
                    make_float4(e1s[4*q+0], e1s[4*q+1], e1s[4*q+2], e1s[4*q+3]);
            }
        }

        // ---- layer 3 (A frags 28..37) ----
        unsigned B3[4][4];
        #pragma unroll
        for (int tt = 0; tt < 2; ++tt) {
            unsigned L0 = pkrtz(e0s[8*tt+0], e0s[8*tt+1]), L1 = pkrtz(e0s[8*tt+2], e0s[8*tt+3]);
            unsigned H0 = pkrtz(e0s[8*tt+4], e0s[8*tt+5]), H1 = pkrtz(e0s[8*tt+6], e0s[8*tt+7]);
            plswap(L0, H0); plswap(L1, H1);
            B3[tt][0] = L0; B3[tt][1] = L1; B3[tt][2] = H0; B3[tt][3] = H1;
            unsigned M0 = pkrtz(e1s[8*tt+0], e1s[8*tt+1]), M1 = pkrtz(e1s[8*tt+2], e1s[8*tt+3]);
            unsigned N0 = pkrtz(e1s[8*tt+4], e1s[8*tt+5]), N1 = pkrtz(e1s[8*tt+6], e1s[8*tt+7]);
            plswap(M0, N0); plswap(M1, N1);
            B3[2+tt][0] = M0; B3[2+tt][1] = M1; B3[2+tt][2] = N0; B3[2+tt][3] = N1;
        }
        f32x16 a30 = zero16(), a31 = zero16();
        #pragma unroll
        for (int t = 0; t < 4; ++t) {
            f16x8 bt = frag4(B3[t][0], B3[t][1], B3[t][2], B3[t][3]);
            a30 = __builtin_amdgcn_mfma_f32_32x32x16_f16(
                *(const f16x8*)(myA + (28 + t) * 512), bt, a30, 0, 0, 0);
            a31 = __builtin_amdgcn_mfma_f32_32x32x16_f16(
                *(const f16x8*)(myA + (33 + t) * 512), bt, a31, 0, 0, 0);
        }
        {
            f16x8 bb = frag4(bias_b0, 0u, 0u, 0u);
            a30 = __builtin_amdgcn_mfma_f32_32x32x16_f16(
                *(const f16x8*)(myA + 32 * 512), bb, a30, 0, 0, 0);
            a31 = __builtin_amdgcn_mfma_f32_32x32x16_f16(
                *(const f16x8*)(myA + 37 * 512), bb, a31, 0, 0, 0);
        }

        // ---- layer 4: scale = tanh(h3 . W4), in-lane 32-FMA + xor-32 ----
        float partial = 0.0f;
        const float4* w4p = reinterpret_cast<const float4*>(sW4f + hi * 32);
        #pragma unroll
        for (int q = 0; q < 4; ++q) {
            const float4 w0 = w4p[q];       // m=0, r=4q..4q+3
            const float4 w1 = w4p[4 + q];   // m=1
            partial = fmaf(silu_f(a30[4*q+0]), w0.x, partial);
            partial = fmaf(silu_f(a30[4*q+1]), w0.y, partial);
            partial = fmaf(silu_f(a30[4*q+2]), w0.z, partial);
            partial = fmaf(silu_f(a30[4*q+3]), w0.w, partial);
            partial = fmaf(silu_f(a31[4*q+0]), w1.x, partial);
            partial = fmaf(silu_f(a31[4*q+1]), w1.y, partial);
            partial = fmaf(silu_f(a31[4*q+2]), w1.z, partial);
            partial = fmaf(silu_f(a31[4*q+3]), w1.w, partial);
        }
        const float tot = partial + __shfl_xor(partial, 32);
        const float scale = tanhf(tot);

        if (valid && hi == 0) {
            out_radial[e] = radial;
            const float k = scale / (sqrtf(radial) + 1e-8f);
            out_trans[e*3+0] = dx0 * k;
            out_trans[e*3+1] = dx1 * k;
            out_trans[e*3+2] = dx2 * k;
        }
    }
}

extern "C" void kernel_launch(void* const* d_in, const int* in_sizes, int n_in,
                              void* d_out, int out_size, void* d_ws, size_t ws_size,
                              hipStream_t stream) {
    const float* x   = (const float*)d_in[0];
    const float* hh  = (const float*)d_in[1];
    const int* src_idx = (const int*)d_in[2];
    const int* dst_idx = (const int*)d_in[3];
    const float* W1  = (const float*)d_in[4];
    const float* b1  = (const float*)d_in[5];
    const float* W2  = (const float*)d_in[6];
    const float* b2  = (const float*)d_in[7];
    const float* W3  = (const float*)d_in[8];
    const float* b3  = (const float*)d_in[9];
    const float* W4  = (const float*)d_in[10];

    const int E = in_sizes[2];

    float* out_radial = (float*)d_out;            // [E]
    float* out_trans  = out_radial + (long)E;     // [E,3]
    float* out_ef     = out_radial + (long)E * 4; // [E,64]

    // 256 thr (4 waves), 39.25KB LDS -> 4 blocks/CU resident, 16 waves/CU.
    dim3 grid(1024), block(256);
    egnn_edge_kernel<<<grid, block, 0, stream>>>(
        x, hh, src_idx, dst_idx, W1, b1, W2, b2, W3, b3, W4,
        out_radial, out_trans, out_ef, E);
}